// Round 3
// baseline (228.842 us; speedup 1.0000x reference)
//
#include <hip/hip_runtime.h>
#include <stdint.h>

#define D_MODEL 768
#define E3      2304
#define NCTX    2048
#define NH      12
#define HD      64
#define MROWS   4096  // 2*2048

typedef __attribute__((ext_vector_type(8))) short short8;   // 8 bf16 — MFMA x32 A/B frag
typedef __attribute__((ext_vector_type(4))) short bf16x4;   // 4 bf16 — MFMA x16 A/B frag
typedef __attribute__((ext_vector_type(4))) float f32x4;    // MFMA C/D frag

typedef __attribute__((address_space(3))) uint32_t lds_u32;
typedef __attribute__((address_space(1))) uint32_t glob_u32;

__device__ __forceinline__ void async_copy16(const void* g, void* l) {
    __builtin_amdgcn_global_load_lds((const glob_u32*)(uintptr_t)g,
                                     (lds_u32*)(uint32_t)(uintptr_t)l, 16, 0, 0);
}

__device__ __forceinline__ unsigned short f2bf(float f) {  // RNE fp32->bf16
    uint32_t u = __builtin_bit_cast(uint32_t, f);
    u += 0x7fffu + ((u >> 16) & 1u);
    return (unsigned short)(u >> 16);
}

__device__ __forceinline__ float fast_exp2(float x) {
#if __has_builtin(__builtin_amdgcn_exp2f)
    return __builtin_amdgcn_exp2f(x);
#else
    return __expf(x * 0.6931471805599453f);
#endif
}

// ---------------- cast fp32 -> bf16 ----------------
__global__ void cast_bf16_kernel(const float* __restrict__ in, unsigned short* __restrict__ out) {
    int i = blockIdx.x * blockDim.x + threadIdx.x;
    float4 v = ((const float4*)in)[i];
    ushort4 o;
    o.x = f2bf(v.x); o.y = f2bf(v.y); o.z = f2bf(v.z); o.w = f2bf(v.w);
    ((ushort4*)out)[i] = o;
}

// ---------------- QKV GEMM (unchanged from r2) ----------------
// K cols plain -> Z; Q cols scaled by log2e/sqrt(768) -> Z; V written transposed -> Vt[nh][d][key]
__global__ __launch_bounds__(256) void qkv_gemm(const unsigned short* __restrict__ A,
                                                const unsigned short* __restrict__ B,
                                                const float* __restrict__ bias,
                                                unsigned short* __restrict__ Z,
                                                unsigned short* __restrict__ Vt) {
    __shared__ __attribute__((aligned(16))) unsigned short sA[128 * 32];
    __shared__ __attribute__((aligned(16))) unsigned short sB[128 * 32];

    const int tid  = threadIdx.x;
    const int wave = tid >> 6;
    const int lane = tid & 63;
    const int quad = lane >> 4;
    const int l15  = lane & 15;
    const int wm   = (wave >> 1) << 6;
    const int wn   = (wave & 1) << 6;
    const int row0 = blockIdx.y * 128;
    const int col0 = blockIdx.x * 128;

    const int srow   = lane >> 2;
    const int schunk = (lane & 3) * 8;

    f32x4 acc[4][4] = {};

    for (int k0 = 0; k0 < D_MODEL; k0 += 32) {
        __syncthreads();
#pragma unroll
        for (int t = 0; t < 2; ++t) {
            const int rbase = t * 64 + wave * 16;
            async_copy16(A + (size_t)(row0 + rbase + srow) * D_MODEL + k0 + schunk, &sA[rbase * 32]);
            async_copy16(B + (size_t)(col0 + rbase + srow) * D_MODEL + k0 + schunk, &sB[rbase * 32]);
        }
        __syncthreads();

        short8 aF[4], bF[4];
#pragma unroll
        for (int i = 0; i < 4; ++i)
            aF[i] = *(const short8*)&sA[(wm + i * 16 + l15) * 32 + quad * 8];
#pragma unroll
        for (int i = 0; i < 4; ++i)
            bF[i] = *(const short8*)&sB[(wn + i * 16 + l15) * 32 + quad * 8];
#pragma unroll
        for (int i = 0; i < 4; ++i)
#pragma unroll
            for (int j = 0; j < 4; ++j)
                acc[i][j] = __builtin_amdgcn_mfma_f32_16x16x32_bf16(aF[i], bF[j], acc[i][j], 0, 0, 0);
    }

    if (col0 >= 2 * D_MODEL) {
        const int nh_ = (row0 >> 11) * NH + ((col0 - 2 * D_MODEL + wn) >> 6);
        const int keyBase = (row0 & (NCTX - 1)) + wm;
#pragma unroll
        for (int j = 0; j < 4; ++j) {
            const int col = col0 + wn + j * 16 + l15;
            const float bv = bias[col];
            const int d = (col - 2 * D_MODEL) & 63;
#pragma unroll
            for (int i = 0; i < 4; ++i) {
                const int key = keyBase + i * 16 + quad * 4;
                ushort4 w4;
                w4.x = f2bf(acc[i][j][0] + bv);
                w4.y = f2bf(acc[i][j][1] + bv);
                w4.z = f2bf(acc[i][j][2] + bv);
                w4.w = f2bf(acc[i][j][3] + bv);
                *(ushort4*)&Vt[((size_t)nh_ * HD + d) * NCTX + key] = w4;
            }
        }
    } else {
        const float zscale = (col0 >= D_MODEL) ? (0.036084391824351615f * 1.4426950408889634f) : 1.0f;
#pragma unroll
        for (int j = 0; j < 4; ++j) {
            const int col = col0 + wn + j * 16 + l15;
            const float bv = bias[col];
#pragma unroll
            for (int i = 0; i < 4; ++i) {
                const int row = row0 + wm + i * 16 + quad * 4;
#pragma unroll
                for (int r = 0; r < 4; ++r)
                    Z[(size_t)(row + r) * E3 + col] = f2bf((acc[i][j][r] + bv) * zscale);
            }
        }
    }
}

// ---------------- flash attention, key-split 4 waves/block ----------------
// Block = 4 waves, one q32-tile pair {j, 63-j} (33 key64-units, uniform).
// Wave w handles kb ≡ w (mod 4). S^T trick: S^T=K·Q^T puts P in the x16 MFMA
// A-layout in registers (no LDS round-trip). m fixed at 0; l deferred.
// End: one LDS partial-reduce, wave w finalizes m-tile w.
#if __has_builtin(__builtin_amdgcn_mfma_f32_16x16x16bf16_1k)
#define HAVE_MFMA16 1
#else
#define HAVE_MFMA16 0
#endif

__global__ __launch_bounds__(256, 3) void attn_kernel(const unsigned short* __restrict__ Zb,
                                                      const unsigned short* __restrict__ Vt,
                                                      float* __restrict__ out) {
    // reduce buffer: [owner mt][contrib slot][j: 16 o-elems + 1 lsum][lane] = 52.2 KB
    __shared__ __attribute__((aligned(16))) float red[4][3][17][64];

    const int tid  = threadIdx.x;
    const int wave = tid >> 6;
    const int lane = tid & 63;
    const int quad = lane >> 4;
    const int l15  = lane & 15;
    const int b    = blockIdx.x;
    const int nh   = b % (2 * NH);
    const int j    = b / (2 * NH);          // 0..31
    const int n    = nh / NH;
    const int h    = nh - n * NH;

    const int tq[2] = { j, 63 - j };                   // q32-tile indices
    const int wk[2] = { j / 2 + 1, (63 - j) / 2 + 1 }; // 64-key blocks per tile

    const size_t baseRow = (size_t)n * NCTX;
    const unsigned short* Qp = Zb + baseRow * E3 + D_MODEL + h * HD;
    const unsigned short* Kp = Zb + baseRow * E3 + h * HD;
    const unsigned short* Vp = Vt + (size_t)nh * HD * NCTX;

#if !HAVE_MFMA16
    // wave-private P staging, aliases red (only used before the first barrier)
    unsigned short* sPw = ((unsigned short*)red) + wave * (16 * 72);
#endif

    f32x4 o[2][2][4] = {};   // [tile][m][dt]: O[q=quad*4+r][d=dt*16+l15]
    float lsum[2][2] = {};   // per-lane partial row-sum for q=l15

    for (int kb = wave; kb < wk[1]; kb += 4) {
        // K A-frags: K[key=ct*16+l15][d=ks*32+quad*8..+7], 16B contiguous
        short8 kf[2][4];
#pragma unroll
        for (int ks = 0; ks < 2; ++ks)
#pragma unroll
            for (int ct = 0; ct < 4; ++ct)
                kf[ks][ct] = *(const short8*)&Kp[(size_t)(kb * 64 + ct * 16 + l15) * E3 + ks * 32 + quad * 8];

#pragma unroll
        for (int tl = 0; tl < 2; ++tl) {
            if (kb >= wk[tl]) continue;               // wave-uniform
            const bool diag = (kb == wk[tl] - 1);
            const int q0 = tq[tl] * 32;
#pragma unroll
            for (int m = 0; m < 2; ++m) {
                // Q B-frags (L1/L2-resident reload, saves registers)
                const unsigned short* qrow = Qp + (size_t)(q0 + m * 16 + l15) * E3;
                short8 qf0 = *(const short8*)&qrow[quad * 8];
                short8 qf1 = *(const short8*)&qrow[32 + quad * 8];

                // S^T = K Q^T: lane holds S[q=l15][key=kb*64+ct*16+quad*4+r]
                f32x4 s[4] = {};
#pragma unroll
                for (int ct = 0; ct < 4; ++ct) {
                    s[ct] = __builtin_amdgcn_mfma_f32_16x16x32_bf16(kf[0][ct], qf0, s[ct], 0, 0, 0);
                    s[ct] = __builtin_amdgcn_mfma_f32_16x16x32_bf16(kf[1][ct], qf1, s[ct], 0, 0, 0);
                }

                const int qg = q0 + m * 16 + l15;     // this lane's q row
                float psum = 0.0f;
#if HAVE_MFMA16
                bf16x4 pA[4];
#endif
#pragma unroll
                for (int ct = 0; ct < 4; ++ct) {
                    float pv[4];
#pragma unroll
                    for (int r = 0; r < 4; ++r) {
                        const int key = kb * 64 + ct * 16 + quad * 4 + r;
                        float sv = s[ct][r];
                        if (diag && key > qg) sv = -INFINITY;
                        pv[r] = fast_exp2(sv);
                        psum += pv[r];
                    }
#if HAVE_MFMA16
                    pA[ct][0] = (short)f2bf(pv[0]); pA[ct][1] = (short)f2bf(pv[1]);
                    pA[ct][2] = (short)f2bf(pv[2]); pA[ct][3] = (short)f2bf(pv[3]);
#else
                    ushort4 w4;
                    w4.x = f2bf(pv[0]); w4.y = f2bf(pv[1]); w4.z = f2bf(pv[2]); w4.w = f2bf(pv[3]);
                    *(ushort4*)&sPw[l15 * 72 + ct * 16 + quad * 4] = w4;
#endif
                }
                lsum[tl][m] += psum;

                // O += P V   (O[q][d], q=quad*4+r rows, d=dt*16+l15 cols)
#if HAVE_MFMA16
#pragma unroll
                for (int ct = 0; ct < 4; ++ct) {
                    bf16x4 vfr[4];
#pragma unroll
                    for (int dt = 0; dt < 4; ++dt)
                        vfr[dt] = *(const bf16x4*)&Vp[(size_t)(dt * 16 + l15) * NCTX + kb * 64 + ct * 16 + quad * 4];
#pragma unroll
                    for (int dt = 0; dt < 4; ++dt)
                        o[tl][m][dt] = __builtin_amdgcn_mfma_f32_16x16x16bf16_1k(pA[ct], vfr[dt], o[tl][m][dt], 0, 0, 0);
                }
#else
                const short8 pf0 = *(const short8*)&sPw[l15 * 72 + quad * 8];
                const short8 pf1 = *(const short8*)&sPw[l15 * 72 + 32 + quad * 8];
#pragma unroll
                for (int dt = 0; dt < 4; ++dt) {
                    const short8 vf0 = *(const short8*)&Vp[(size_t)(dt * 16 + l15) * NCTX + kb * 64 + quad * 8];
                    const short8 vf1 = *(const short8*)&Vp[(size_t)(dt * 16 + l15) * NCTX + kb * 64 + 32 + quad * 8];
                    o[tl][m][dt] = __builtin_amdgcn_mfma_f32_16x16x32_bf16(pf0, vf0, o[tl][m][dt], 0, 0, 0);
                    o[tl][m][dt] = __builtin_amdgcn_mfma_f32_16x16x32_bf16(pf1, vf1, o[tl][m][dt], 0, 0, 0);
                }
#endif
            }
        }
    }

    // reduce lsum across quads: every lane then holds full-partial l for q=l15
#pragma unroll
    for (int tl = 0; tl < 2; ++tl)
#pragma unroll
        for (int m = 0; m < 2; ++m) {
            float l = lsum[tl][m];
            l += __shfl_xor(l, 16);
            l += __shfl_xor(l, 32);
            lsum[tl][m] = l;
        }

    // grab own m-tile before writing partials
    f32x4 oo[4];
    float lown = 0.0f;
#pragma unroll
    for (int mt = 0; mt < 4; ++mt)
        if (wave == mt) {
            const int tl = mt >> 1, m = mt & 1;
#pragma unroll
            for (int dt = 0; dt < 4; ++dt) oo[dt] = o[tl][m][dt];
            lown = lsum[tl][m];
        }

    __syncthreads();  // (path ii: all waves done with sPw region of red)

#pragma unroll
    for (int mt = 0; mt < 4; ++mt) {
        if (mt == wave) continue;                       // wave-uniform
        const int slot = wave - (wave > mt ? 1 : 0);
        const int tl = mt >> 1, m = mt & 1;
#pragma unroll
        for (int dt = 0; dt < 4; ++dt)
#pragma unroll
            for (int r = 0; r < 4; ++r)
                red[mt][slot][dt * 4 + r][lane] = o[tl][m][dt][r];
        red[mt][slot][16][lane] = lsum[tl][m];
    }
    __syncthreads();

    // owner wave finalizes m-tile = wave
    {
        float l = lown;
#pragma unroll
        for (int slot = 0; slot < 3; ++slot) {
            l += red[wave][slot][16][lane];
#pragma unroll
            for (int dt = 0; dt < 4; ++dt)
#pragma unroll
                for (int r = 0; r < 4; ++r)
                    oo[dt][r] += red[wave][slot][dt * 4 + r][lane];
        }
        const float linv = 1.0f / l;                    // valid for q=l15
        const int tqv = (wave >> 1) ? (63 - j) : j;
        const int q0 = tqv * 32 + (wave & 1) * 16;
#pragma unroll
        for (int r = 0; r < 4; ++r) {
            const float inv = __shfl(linv, quad * 4 + r);  // lane (quad*4+r) has l15==q
            const size_t row = baseRow + q0 + quad * 4 + r;
#pragma unroll
            for (int dt = 0; dt < 4; ++dt)
                out[row * D_MODEL + h * HD + dt * 16 + l15] = oo[dt][r] * inv;
        }
    }
}

extern "C" void kernel_launch(void* const* d_in, const int* in_sizes, int n_in,
                              void* d_out, int out_size, void* d_ws, size_t ws_size,
                              hipStream_t stream) {
    const float* x = (const float*)d_in[0];   // [2,2048,768]
    const float* W = (const float*)d_in[1];   // [2304,768]
    const float* b = (const float*)d_in[2];   // [2304]
    float* out = (float*)d_out;

    unsigned short* xb = (unsigned short*)d_ws;                    // 4096*768
    unsigned short* Wb = xb + (size_t)MROWS * D_MODEL;             // 2304*768
    unsigned short* Zb = Wb + (size_t)E3 * D_MODEL;                // 4096*2304 (V third unused)
    unsigned short* Vt = Zb + (size_t)MROWS * E3;                  // 24*64*2048

    cast_bf16_kernel<<<dim3((MROWS * D_MODEL / 4) / 256), 256, 0, stream>>>(x, xb);
    cast_bf16_kernel<<<dim3((E3 * D_MODEL / 4) / 256), 256, 0, stream>>>(W, Wb);
    qkv_gemm<<<dim3(E3 / 128, MROWS / 128), 256, 0, stream>>>(xb, Wb, b, Zb, Vt);
    attn_kernel<<<dim3(2 * NH * 32), 256, 0, stream>>>(Zb, Vt, out);
}